// Round 6
// baseline (51.680 us; speedup 1.0000x reference)
//
#include <hip/hip_runtime.h>
#include <stdint.h>

typedef unsigned long long u64;
typedef unsigned int u32;
typedef unsigned char u8;

#define Bn 32
#define Nn 320
#define WPN 5                 // 64-bit words per 320-bit row
#define ROWW 6                // padded row stride in u64 (48 B)
#define MAXD 10
#define NH 8
#define CH 16                 // sources per block (4 per wave)
#define NCHUNK (Nn / CH)      // 20
#define TPB 256               // four waves per block
#define ESTR 12               // emb_s row stride in floats
#define IDXSTR 336            // idx_s row stride in bytes
#define MASK20 ((1u << 20) - 1u)

// 16-lane (DPP row) OR-reduce step: VALU only, no DS-pipe traffic.
template<int CTRL> __device__ __forceinline__ u64 ror_or64(u64 v) {
    u32 lo = (u32)v, hi = (u32)(v >> 32);
    lo |= (u32)__builtin_amdgcn_update_dpp(0, (int)lo, CTRL, 0xF, 0xF, true);
    hi |= (u32)__builtin_amdgcn_update_dpp(0, (int)hi, CTRL, 0xF, 0xF, true);
    return ((u64)hi << 32) | lo;
}
template<int CTRL> __device__ __forceinline__ int ror_add(int v) {
    return v + __builtin_amdgcn_update_dpp(0, v, CTRL, 0xF, 0xF, true);
}
#define ROW_ROR_1 0x121
#define ROW_ROR_2 0x122
#define ROW_ROR_4 0x124
#define ROW_ROR_8 0x128

__device__ __forceinline__ bool detect_byte_mode(const u32* a32) {
    int lane = threadIdx.x & 63;
    u32 or0 = 0, or1 = 0;
    #pragma unroll
    for (int k = 0; k < 16; ++k) {
        u32 v = a32[lane + k * 64];
        or0 |= v & 0x000000FFu;
        or1 |= v & 0x0000FF00u;
    }
    bool a0 = __any(or0 != 0);
    bool a1 = __any(or1 != 0);
    return a0 && a1;
}

// ---------------------------------------------------------------------------
// Single fused kernel: in-block adjacency pack + BFS + write.
// 640 blocks x 256 threads (graph x 16-source chunk; wave wv owns sources
// wv*4..wv*4+3; 16 lanes per source = one DPP row). Each block packs its
// graph's raw bool adjacency straight into LDS bitmask rows (L2-resident
// after first touch; pack VALU rides the idle vector pipe) -- no build_adj
// dispatch, no workspace round-trip. Frontier union + group counts via DPP
// row-rotate OR/ADD. No barrier after BFS: waves desync into the write.
// ---------------------------------------------------------------------------
__global__ __launch_bounds__(TPB) void bfs_write(
        const u8* __restrict__ a8,
        const int* __restrict__ nn_,
        const float* __restrict__ emb,
        float4* __restrict__ out4) {
    bool bytemode = detect_byte_mode((const u32*)a8);
    int blk = blockIdx.x;
    int b = blk / NCHUNK, chunk = blk % NCHUNK;
    int t = threadIdx.x;
    int wv = t >> 6;
    int lane = t & 63;
    int s = lane >> 4;            // source-in-wave 0..3 (one DPP row)
    int k = lane & 15;            // segment 0..15 (20 nodes each)
    int r = wv * 4 + s;           // idx row 0..15

    __shared__ __align__(16) u64 adj_s[Nn * ROWW];    // 15360 B row-major
    __shared__ __align__(16) u8 idx_s[CH][IDXSTR];    // 5376 B
    __shared__ float emb_s[(MAXD + 2) * ESTR];        // 576 B

    if (t < 96) emb_s[(t >> 3) * ESTR + (t & 7)] = emb[t];

    int nn = nn_[b];

    // ---- pack adjacency directly into LDS (replaces build_adj + staging) ----
    #pragma unroll
    for (int it = 0; it < 8; ++it) {
        int i = it * TPB + t;                 // word index in [0, 1920)
        if (i < Nn * ROWW) {
            int w = i % ROWW;
            int j = i / ROWW;
            u64 bits = 0ull;
            if (w < WPN && j < nn) {
                int jbase = w * 64;
                int lim = nn - jbase; if (lim > 64) lim = 64;
                if (lim > 0) {
                    long base = ((long)(b * Nn + j)) * Nn + jbase;
                    if (bytemode) {
                        const uint4* p = (const uint4*)(a8 + base);   // 64B
                        #pragma unroll
                        for (int v = 0; v < 4; ++v) {
                            uint4 x = p[v];
                            u32 n0 = ((x.x & 0x01010101u) * 0x01020408u) >> 24;
                            u32 n1 = ((x.y & 0x01010101u) * 0x01020408u) >> 24;
                            u32 n2 = ((x.z & 0x01010101u) * 0x01020408u) >> 24;
                            u32 n3 = ((x.w & 0x01010101u) * 0x01020408u) >> 24;
                            u64 nib = (u64)((n0 & 0xF) | ((n1 & 0xF) << 4) |
                                            ((n2 & 0xF) << 8) | ((n3 & 0xF) << 12));
                            bits |= nib << (v * 16);
                        }
                    } else {
                        const uint4* p = (const uint4*)(((const u32*)a8) + base);
                        #pragma unroll
                        for (int v = 0; v < 16; ++v) {
                            uint4 x = p[v];
                            u64 nib = (u64)((x.x != 0u) | ((x.y != 0u) << 1) |
                                            ((x.z != 0u) << 2) | ((x.w != 0u) << 3));
                            bits |= nib << (v * 4);
                        }
                    }
                    if (lim < 64) bits &= (1ull << lim) - 1ull;
                }
            }
            adj_s[i] = bits;
        }
    }
    // zero idx tile (1344 u32)
    #pragma unroll
    for (int it = 0; it < 6; ++it) {
        int i = it * TPB + t;
        if (i < (CH * IDXSTR) / 4) ((u32*)idx_s)[i] = 0;
    }
    __syncthreads();

    // ---- BFS: wave-independent from here ----
    u64 valid[WPN];
    #pragma unroll
    for (int w = 0; w < WPN; ++w) {
        int c = nn - w * 64;
        valid[w] = (c >= 64) ? ~0ull : ((c <= 0) ? 0ull : ((1ull << c) - 1ull));
    }
    int sg = chunk * CH + r;
    u64 cur[WPN] = {0,0,0,0,0}, vis[WPN] = {0,0,0,0,0};
    if (sg < nn) {
        cur[sg >> 6] = 1ull << (sg & 63);
        vis[sg >> 6] = cur[sg >> 6];
        if (k == 0) idx_s[r][sg] = 1;     // dist 0 -> emb idx 1
    }

    int base = 20 * k, w0 = base >> 6, sh = base & 63;
    u8* myseg = &idx_s[r][base];

    int level = 1;
    while (level <= Nn) {
        u64 unv[WPN];
        #pragma unroll
        for (int w = 0; w < WPN; ++w) unv[w] = valid[w] & ~vis[w];
        u32 segf, segu;
        {
            u64 f = cur[w0] >> sh, u = unv[w0] >> sh;
            if (sh > 44) { f |= cur[w0 + 1] << (64 - sh); u |= unv[w0 + 1] << (64 - sh); }
            segf = (u32)f & MASK20; segu = (u32)u & MASK20;
        }
        int fc = __popc(segf), uw = __popc(segu);
        fc = ror_add<ROW_ROR_1>(fc); fc = ror_add<ROW_ROR_2>(fc);
        fc = ror_add<ROW_ROR_4>(fc); fc = ror_add<ROW_ROR_8>(fc);
        uw = ror_add<ROW_ROR_1>(uw); uw = ror_add<ROW_ROR_2>(uw);
        uw = ror_add<ROW_ROR_4>(uw); uw = ror_add<ROW_ROR_8>(uw);
        if (!__any(fc != 0)) break;

        u64 nxt[WPN] = {0,0,0,0,0};
        if (fc > 0 && uw > 0) {
            if (fc <= uw) {
                // top-down: whole-row reads of my segment's frontier bits
                u32 m = segf;
                while (m) {
                    int j0 = base + __builtin_ctz(m); m &= m - 1;
                    int j1 = j0;
                    if (m) { j1 = base + __builtin_ctz(m); m &= m - 1; }
                    const u64* r0 = adj_s + j0 * ROWW;
                    const u64* r1 = adj_s + j1 * ROWW;
                    ulonglong2 a0 = *(const ulonglong2*)r0;
                    ulonglong2 a1 = *(const ulonglong2*)(r0 + 2);
                    u64 a4 = r0[4];
                    ulonglong2 b0 = *(const ulonglong2*)r1;
                    ulonglong2 b1 = *(const ulonglong2*)(r1 + 2);
                    u64 b4 = r1[4];
                    nxt[0] |= a0.x | b0.x; nxt[1] |= a0.y | b0.y;
                    nxt[2] |= a1.x | b1.x; nxt[3] |= a1.y | b1.y;
                    nxt[4] |= a4 | b4;
                }
            } else {
                // bottom-up over my unvisited segment
                u32 m = segu;
                while (m) {
                    int p0 = __builtin_ctz(m); m &= m - 1;
                    int p1 = p0; bool h = (m != 0u);
                    if (h) { p1 = __builtin_ctz(m); m &= m - 1; }
                    int j0 = base + p0, j1 = base + p1;
                    const u64* r0 = adj_s + j0 * ROWW;
                    const u64* r1 = adj_s + j1 * ROWW;
                    ulonglong2 a0 = *(const ulonglong2*)r0;
                    ulonglong2 a1 = *(const ulonglong2*)(r0 + 2);
                    u64 a4 = r0[4];
                    ulonglong2 b0 = *(const ulonglong2*)r1;
                    ulonglong2 b1 = *(const ulonglong2*)(r1 + 2);
                    u64 b4 = r1[4];
                    u64 t0 = (a0.x & cur[0]) | (a0.y & cur[1]) | (a1.x & cur[2]) |
                             (a1.y & cur[3]) | (a4 & cur[4]);
                    u64 t1 = (b0.x & cur[0]) | (b0.y & cur[1]) | (b1.x & cur[2]) |
                             (b1.y & cur[3]) | (b4 & cur[4]);
                    if (t0) nxt[j0 >> 6] |= 1ull << (j0 & 63);
                    if (h && t1) nxt[j1 >> 6] |= 1ull << (j1 & 63);
                }
            }
            // union across the source's 16 lanes: DPP row-rotate ORs (VALU)
            #pragma unroll
            for (int w = 0; w < WPN; ++w) {
                u64 v = nxt[w];
                v = ror_or64<ROW_ROR_1>(v);
                v = ror_or64<ROW_ROR_2>(v);
                v = ror_or64<ROW_ROR_4>(v);
                v = ror_or64<ROW_ROR_8>(v);
                nxt[w] = v & unv[w];
            }
            u64 any = nxt[0] | nxt[1] | nxt[2] | nxt[3] | nxt[4];
            if (any) {
                u8 val = (u8)((level < MAXD ? level : MAXD) + 1);
                u64 f = nxt[w0] >> sh;
                if (sh > 44) f |= nxt[w0 + 1] << (64 - sh);
                u32 segn = (u32)f & MASK20;
                while (segn) { int p = __builtin_ctz(segn); segn &= segn - 1; myseg[p] = val; }
                #pragma unroll
                for (int w = 0; w < WPN; ++w) vis[w] |= nxt[w];
            }
        }
        #pragma unroll
        for (int w = 0; w < WPN; ++w) cur[w] = nxt[w];
        ++level;
    }
    // NO barrier: each wave reads only its own idx rows below; the faster
    // wave starts its store stream immediately.

    // ---- write phase: my wave's 4 rows x 640 float4 ----
    float4* gout = out4 + (size_t)(b * Nn + chunk * CH) * (Nn * NH / 4);
    #pragma unroll
    for (int r2 = 0; r2 < 4; ++r2) {
        int rr = wv * 4 + r2;
        const u8* irow = idx_s[rr];
        float4* rowout = gout + rr * (Nn * NH / 4);
        #pragma unroll
        for (int i = 0; i < 10; ++i) {
            int f = i * 64 + lane;                // f4 index in row, 0..639
            int e = irow[f >> 1];
            const float* ep = emb_s + e * ESTR + ((f & 1) << 2);
            rowout[f] = *(const float4*)ep;
        }
    }
}

extern "C" void kernel_launch(void* const* d_in, const int* in_sizes, int n_in,
                              void* d_out, int out_size, void* d_ws, size_t ws_size,
                              hipStream_t stream) {
    const u8*    adj = (const u8*)d_in[0];
    const int*   nn  = (const int*)d_in[1];
    const float* emb = (const float*)d_in[2];
    (void)d_ws; (void)ws_size;

    bfs_write<<<Bn * NCHUNK, TPB, 0, stream>>>(adj, nn, emb, (float4*)d_out);
}

// Round 7
// 30.091 us; speedup vs baseline: 1.7174x; 1.7174x over previous
//
#include <hip/hip_runtime.h>
#include <stdint.h>

typedef unsigned long long u64;
typedef unsigned int u32;
typedef unsigned char u8;

#define Bn 32
#define Nn 320
#define WPN 5                 // 64-bit words per 320-bit row
#define ROWW 6                // padded row stride in u64 (48 B)
#define MAXD 10
#define NH 8
#define ADJP_WORDS (Bn * Nn * ROWW)   // 61440 u64 (padded row-major)
#define CH 16                 // sources per block (4 per wave)
#define NCHUNK (Nn / CH)      // 20
#define TPB 256               // four waves per block
#define ESTR 12               // emb_s row stride in floats
#define IDXSTR 336            // idx_s row stride in bytes
#define MASK20 ((1u << 20) - 1u)

// 16-lane (DPP row) OR-reduce step: VALU only, no DS-pipe traffic.
template<int CTRL> __device__ __forceinline__ u64 ror_or64(u64 v) {
    u32 lo = (u32)v, hi = (u32)(v >> 32);
    lo |= (u32)__builtin_amdgcn_update_dpp(0, (int)lo, CTRL, 0xF, 0xF, true);
    hi |= (u32)__builtin_amdgcn_update_dpp(0, (int)hi, CTRL, 0xF, 0xF, true);
    return ((u64)hi << 32) | lo;
}
#define ROW_ROR_1 0x121
#define ROW_ROR_2 0x122
#define ROW_ROR_4 0x124
#define ROW_ROR_8 0x128

// ---------------------------------------------------------------------------
// Kernel 1: pack adjacency into PADDED ROW-MAJOR u64 bitmask rows.
// ---------------------------------------------------------------------------
__device__ __forceinline__ bool detect_byte_mode(const u32* a32) {
    int lane = threadIdx.x & 63;
    u32 or0 = 0, or1 = 0;
    #pragma unroll
    for (int k = 0; k < 16; ++k) {
        u32 v = a32[lane + k * 64];
        or0 |= v & 0x000000FFu;
        or1 |= v & 0x0000FF00u;
    }
    bool a0 = __any(or0 != 0);
    bool a1 = __any(or1 != 0);
    return a0 && a1;
}

__global__ __launch_bounds__(256) void build_adj(
        const u8* __restrict__ a8,
        const int* __restrict__ nn_,
        u64* __restrict__ adjW) {
    bool bytemode = detect_byte_mode((const u32*)a8);
    int t = blockIdx.x * blockDim.x + threadIdx.x;
    if (t >= ADJP_WORDS) return;
    int w = t % ROWW;
    int j = (t / ROWW) % Nn;
    int b = t / (ROWW * Nn);
    int nn = nn_[b];
    u64 bits = 0ull;
    if (w < WPN && j < nn) {
        int jbase = w * 64;
        int lim = nn - jbase; if (lim > 64) lim = 64;
        if (lim > 0) {
            long base = ((long)(b * Nn + j)) * Nn + jbase;
            if (bytemode) {
                const uint4* p = (const uint4*)(a8 + base);   // 64B
                #pragma unroll
                for (int v = 0; v < 4; ++v) {
                    uint4 x = p[v];
                    u32 n0 = ((x.x & 0x01010101u) * 0x01020408u) >> 24;
                    u32 n1 = ((x.y & 0x01010101u) * 0x01020408u) >> 24;
                    u32 n2 = ((x.z & 0x01010101u) * 0x01020408u) >> 24;
                    u32 n3 = ((x.w & 0x01010101u) * 0x01020408u) >> 24;
                    u64 nib = (u64)((n0 & 0xF) | ((n1 & 0xF) << 4) |
                                    ((n2 & 0xF) << 8) | ((n3 & 0xF) << 12));
                    bits |= nib << (v * 16);
                }
            } else {
                const uint4* p = (const uint4*)(((const u32*)a8) + base);  // 256B
                #pragma unroll
                for (int v = 0; v < 16; ++v) {
                    uint4 x = p[v];
                    u64 nib = (u64)((x.x != 0u) | ((x.y != 0u) << 1) |
                                    ((x.z != 0u) << 2) | ((x.w != 0u) << 3));
                    bits |= nib << (v * 4);
                }
            }
            if (lim < 64) bits &= (1ull << lim) - 1ull;
        }
    }
    adjW[t] = bits;
}

// ---------------------------------------------------------------------------
// Kernel 2: fused BFS + write (R5 structure, CH=16). 640 blocks x 256 threads
// (graph x 16-source chunk; wave wv owns sources wv*4..wv*4+3; 16 lanes per
// source = one DPP row). cur/vis/unv are ROW-UNIFORM, so frontier/unvisited
// counts come from per-lane popcounts (no cross-lane reduce). 4-wide
// divergent inner loops (12 LDS reads in flight). No barrier after BFS.
// ---------------------------------------------------------------------------
__global__ __launch_bounds__(TPB) void bfs_write(
        const u64* __restrict__ adjW,
        const int* __restrict__ nn_,
        const float* __restrict__ emb,
        float4* __restrict__ out4) {
    int blk = blockIdx.x;
    int b = blk / NCHUNK, chunk = blk % NCHUNK;
    int t = threadIdx.x;
    int wv = t >> 6;
    int lane = t & 63;
    int s = lane >> 4;            // source-in-wave 0..3 (one DPP row)
    int k = lane & 15;            // segment 0..15 (20 nodes each)
    int r = wv * 4 + s;           // idx row 0..15

    __shared__ __align__(16) u64 adj_s[Nn * ROWW];    // 15360 B row-major
    __shared__ __align__(16) u8 idx_s[CH][IDXSTR];    // 5376 B
    __shared__ float emb_s[(MAXD + 2) * ESTR];        // 576 B

    if (t < 96) emb_s[(t >> 3) * ESTR + (t & 7)] = emb[t];

    // stage: 960 uint4 over 4 waves via direct global->LDS (linear dest)
    {
        const uint4* g4 = (const uint4*)(adjW + (size_t)b * (Nn * ROWW));
        uint4* d4 = (uint4*)adj_s;
        #pragma unroll
        for (int it = 0; it < 4; ++it) {
            int i = it * TPB + t;
            if (i < 960) {
#if __has_builtin(__builtin_amdgcn_global_load_lds)
                __builtin_amdgcn_global_load_lds(
                    (const __attribute__((address_space(1))) void*)(g4 + i),
                    (__attribute__((address_space(3))) void*)(d4 + i),
                    16, 0, 0);
#else
                d4[i] = g4[i];
#endif
            }
        }
    }
    // zero idx tile (1344 u32)
    #pragma unroll
    for (int it = 0; it < 6; ++it) {
        int i = it * TPB + t;
        if (i < (CH * IDXSTR) / 4) ((u32*)idx_s)[i] = 0;
    }
    int nn = nn_[b];
    __syncthreads();   // drains vmcnt (global_load_lds) + lgkmcnt

    // ---- BFS: wave-independent from here ----
    u64 valid[WPN];
    #pragma unroll
    for (int w = 0; w < WPN; ++w) {
        int c = nn - w * 64;
        valid[w] = (c >= 64) ? ~0ull : ((c <= 0) ? 0ull : ((1ull << c) - 1ull));
    }
    int sg = chunk * CH + r;
    u64 cur[WPN] = {0,0,0,0,0}, vis[WPN] = {0,0,0,0,0};
    if (sg < nn) {
        cur[sg >> 6] = 1ull << (sg & 63);
        vis[sg >> 6] = cur[sg >> 6];
        if (k == 0) idx_s[r][sg] = 1;     // dist 0 -> emb idx 1
    }

    int base = 20 * k, w0 = base >> 6, sh = base & 63;
    u8* myseg = &idx_s[r][base];

    int level = 1;
    while (level <= Nn) {
        // cur/vis are row-uniform: counts via per-lane popcount, NO reduce.
        u64 unv[WPN];
        int fc = 0, uw = 0;
        #pragma unroll
        for (int w = 0; w < WPN; ++w) {
            unv[w] = valid[w] & ~vis[w];
            fc += __popcll(cur[w]);
            uw += __popcll(unv[w]);
        }
        if (!__any(fc != 0)) break;

        u64 nxt[WPN] = {0,0,0,0,0};
        if (fc > 0 && uw > 0) {
            if (fc <= uw) {
                // top-down: 4-wide over my segment's frontier bits
                u64 f = cur[w0] >> sh;
                if (sh > 44) f |= cur[w0 + 1] << (64 - sh);
                u32 m = (u32)f & MASK20;
                while (m) {
                    int j0 = base + __builtin_ctz(m); m &= m - 1;
                    int j1 = j0, j2 = j0, j3 = j0;
                    if (m) { j1 = base + __builtin_ctz(m); m &= m - 1; }
                    if (m) { j2 = base + __builtin_ctz(m); m &= m - 1; }
                    if (m) { j3 = base + __builtin_ctz(m); m &= m - 1; }
                    const u64* r0 = adj_s + j0 * ROWW;
                    const u64* r1 = adj_s + j1 * ROWW;
                    const u64* r2 = adj_s + j2 * ROWW;
                    const u64* r3 = adj_s + j3 * ROWW;
                    ulonglong2 a0 = *(const ulonglong2*)r0;
                    ulonglong2 a1 = *(const ulonglong2*)(r0 + 2);
                    ulonglong2 b0 = *(const ulonglong2*)r1;
                    ulonglong2 b1 = *(const ulonglong2*)(r1 + 2);
                    ulonglong2 c0 = *(const ulonglong2*)r2;
                    ulonglong2 c1 = *(const ulonglong2*)(r2 + 2);
                    ulonglong2 d0 = *(const ulonglong2*)r3;
                    ulonglong2 d1 = *(const ulonglong2*)(r3 + 2);
                    u64 a4 = r0[4], b4 = r1[4], c4 = r2[4], d4 = r3[4];
                    nxt[0] |= (a0.x | b0.x) | (c0.x | d0.x);
                    nxt[1] |= (a0.y | b0.y) | (c0.y | d0.y);
                    nxt[2] |= (a1.x | b1.x) | (c1.x | d1.x);
                    nxt[3] |= (a1.y | b1.y) | (c1.y | d1.y);
                    nxt[4] |= (a4 | b4) | (c4 | d4);
                }
            } else {
                // bottom-up: 4-wide over my unvisited segment
                u64 u_ = unv[w0] >> sh;
                if (sh > 44) u_ |= unv[w0 + 1] << (64 - sh);
                u32 m = (u32)u_ & MASK20;
                while (m) {
                    int p0 = __builtin_ctz(m); m &= m - 1;
                    int p1 = p0, p2 = p0, p3 = p0;
                    bool h1 = false, h2 = false, h3 = false;
                    if (m) { p1 = __builtin_ctz(m); m &= m - 1; h1 = true; }
                    if (m) { p2 = __builtin_ctz(m); m &= m - 1; h2 = true; }
                    if (m) { p3 = __builtin_ctz(m); m &= m - 1; h3 = true; }
                    int j0 = base + p0, j1 = base + p1;
                    int j2 = base + p2, j3 = base + p3;
                    const u64* r0 = adj_s + j0 * ROWW;
                    const u64* r1 = adj_s + j1 * ROWW;
                    const u64* r2 = adj_s + j2 * ROWW;
                    const u64* r3 = adj_s + j3 * ROWW;
                    ulonglong2 a0 = *(const ulonglong2*)r0;
                    ulonglong2 a1 = *(const ulonglong2*)(r0 + 2);
                    ulonglong2 b0 = *(const ulonglong2*)r1;
                    ulonglong2 b1 = *(const ulonglong2*)(r1 + 2);
                    ulonglong2 c0 = *(const ulonglong2*)r2;
                    ulonglong2 c1 = *(const ulonglong2*)(r2 + 2);
                    ulonglong2 d0 = *(const ulonglong2*)r3;
                    ulonglong2 d1 = *(const ulonglong2*)(r3 + 2);
                    u64 a4 = r0[4], b4 = r1[4], c4 = r2[4], d4 = r3[4];
                    u64 t0 = (a0.x & cur[0]) | (a0.y & cur[1]) | (a1.x & cur[2]) |
                             (a1.y & cur[3]) | (a4 & cur[4]);
                    u64 t1 = (b0.x & cur[0]) | (b0.y & cur[1]) | (b1.x & cur[2]) |
                             (b1.y & cur[3]) | (b4 & cur[4]);
                    u64 t2 = (c0.x & cur[0]) | (c0.y & cur[1]) | (c1.x & cur[2]) |
                             (c1.y & cur[3]) | (c4 & cur[4]);
                    u64 t3 = (d0.x & cur[0]) | (d0.y & cur[1]) | (d1.x & cur[2]) |
                             (d1.y & cur[3]) | (d4 & cur[4]);
                    if (t0) nxt[j0 >> 6] |= 1ull << (j0 & 63);
                    if (h1 && t1) nxt[j1 >> 6] |= 1ull << (j1 & 63);
                    if (h2 && t2) nxt[j2 >> 6] |= 1ull << (j2 & 63);
                    if (h3 && t3) nxt[j3 >> 6] |= 1ull << (j3 & 63);
                }
            }
            // union across the source's 16 lanes: DPP row-rotate ORs (VALU)
            #pragma unroll
            for (int w = 0; w < WPN; ++w) {
                u64 v = nxt[w];
                v = ror_or64<ROW_ROR_1>(v);
                v = ror_or64<ROW_ROR_2>(v);
                v = ror_or64<ROW_ROR_4>(v);
                v = ror_or64<ROW_ROR_8>(v);
                nxt[w] = v & unv[w];
            }
            u64 any = nxt[0] | nxt[1] | nxt[2] | nxt[3] | nxt[4];
            if (any) {
                u8 val = (u8)((level < MAXD ? level : MAXD) + 1);
                u64 f = nxt[w0] >> sh;
                if (sh > 44) f |= nxt[w0 + 1] << (64 - sh);
                u32 segn = (u32)f & MASK20;
                while (segn) { int p = __builtin_ctz(segn); segn &= segn - 1; myseg[p] = val; }
                #pragma unroll
                for (int w = 0; w < WPN; ++w) vis[w] |= nxt[w];
            }
        }
        // bottom break: nothing new anywhere in the wave -> done
        if (!__any((nxt[0] | nxt[1] | nxt[2] | nxt[3] | nxt[4]) != 0)) break;
        #pragma unroll
        for (int w = 0; w < WPN; ++w) cur[w] = nxt[w];
        ++level;
    }
    // NO barrier: each wave reads only its own idx rows below; the faster
    // wave starts its store stream immediately.

    // ---- write phase: my wave's 4 rows x 640 float4 ----
    float4* gout = out4 + (size_t)(b * Nn + chunk * CH) * (Nn * NH / 4);
    #pragma unroll
    for (int r2 = 0; r2 < 4; ++r2) {
        int rr = wv * 4 + r2;
        const u8* irow = idx_s[rr];
        float4* rowout = gout + rr * (Nn * NH / 4);
        #pragma unroll
        for (int i = 0; i < 10; ++i) {
            int f = i * 64 + lane;                // f4 index in row, 0..639
            int e = irow[f >> 1];
            const float* ep = emb_s + e * ESTR + ((f & 1) << 2);
            rowout[f] = *(const float4*)ep;
        }
    }
}

extern "C" void kernel_launch(void* const* d_in, const int* in_sizes, int n_in,
                              void* d_out, int out_size, void* d_ws, size_t ws_size,
                              hipStream_t stream) {
    const u8*    adj = (const u8*)d_in[0];
    const int*   nn  = (const int*)d_in[1];
    const float* emb = (const float*)d_in[2];

    u64* adjW = (u64*)d_ws;

    build_adj<<<(ADJP_WORDS + 255) / 256, 256, 0, stream>>>(adj, nn, adjW);
    bfs_write<<<Bn * NCHUNK, TPB, 0, stream>>>(adjW, nn, emb, (float4*)d_out);
}

// Round 8
// 28.958 us; speedup vs baseline: 1.7847x; 1.0391x over previous
//
#include <hip/hip_runtime.h>
#include <stdint.h>

typedef unsigned long long u64;
typedef unsigned int u32;
typedef unsigned char u8;

#define Bn 32
#define Nn 320
#define WPN 5                 // 64-bit words per 320-bit row
#define ROWW 6                // padded row stride in u64 (48 B)
#define MAXD 10
#define NH 8
#define ADJP_WORDS (Bn * Nn * ROWW)   // 61440 u64 (padded row-major)
#define CH 16                 // sources per block (4 per wave)
#define NCHUNK (Nn / CH)      // 20
#define TPB 256               // four waves per block
#define ESTR 12               // emb_s row stride in floats
#define IDXSTR 336            // idx_s row stride in bytes
#define MASK20 ((1u << 20) - 1u)

// 16-lane (DPP row) OR-reduce step: VALU only, no DS-pipe traffic.
template<int CTRL> __device__ __forceinline__ u64 ror_or64(u64 v) {
    u32 lo = (u32)v, hi = (u32)(v >> 32);
    lo |= (u32)__builtin_amdgcn_update_dpp(0, (int)lo, CTRL, 0xF, 0xF, true);
    hi |= (u32)__builtin_amdgcn_update_dpp(0, (int)hi, CTRL, 0xF, 0xF, true);
    return ((u64)hi << 32) | lo;
}
#define ROW_ROR_1 0x121
#define ROW_ROR_2 0x122
#define ROW_ROR_4 0x124
#define ROW_ROR_8 0x128

// ---------------------------------------------------------------------------
// Kernel 1: pack adjacency into PADDED ROW-MAJOR u64 bitmask rows.
// ---------------------------------------------------------------------------
__device__ __forceinline__ bool detect_byte_mode(const u32* a32) {
    int lane = threadIdx.x & 63;
    u32 or0 = 0, or1 = 0;
    #pragma unroll
    for (int k = 0; k < 16; ++k) {
        u32 v = a32[lane + k * 64];
        or0 |= v & 0x000000FFu;
        or1 |= v & 0x0000FF00u;
    }
    bool a0 = __any(or0 != 0);
    bool a1 = __any(or1 != 0);
    return a0 && a1;
}

__global__ __launch_bounds__(256) void build_adj(
        const u8* __restrict__ a8,
        const int* __restrict__ nn_,
        u64* __restrict__ adjW) {
    bool bytemode = detect_byte_mode((const u32*)a8);
    int t = blockIdx.x * blockDim.x + threadIdx.x;
    if (t >= ADJP_WORDS) return;
    int w = t % ROWW;
    int j = (t / ROWW) % Nn;
    int b = t / (ROWW * Nn);
    int nn = nn_[b];
    u64 bits = 0ull;
    if (w < WPN && j < nn) {
        int jbase = w * 64;
        int lim = nn - jbase; if (lim > 64) lim = 64;
        if (lim > 0) {
            long base = ((long)(b * Nn + j)) * Nn + jbase;
            if (bytemode) {
                const uint4* p = (const uint4*)(a8 + base);   // 64B
                #pragma unroll
                for (int v = 0; v < 4; ++v) {
                    uint4 x = p[v];
                    u32 n0 = ((x.x & 0x01010101u) * 0x01020408u) >> 24;
                    u32 n1 = ((x.y & 0x01010101u) * 0x01020408u) >> 24;
                    u32 n2 = ((x.z & 0x01010101u) * 0x01020408u) >> 24;
                    u32 n3 = ((x.w & 0x01010101u) * 0x01020408u) >> 24;
                    u64 nib = (u64)((n0 & 0xF) | ((n1 & 0xF) << 4) |
                                    ((n2 & 0xF) << 8) | ((n3 & 0xF) << 12));
                    bits |= nib << (v * 16);
                }
            } else {
                const uint4* p = (const uint4*)(((const u32*)a8) + base);  // 256B
                #pragma unroll
                for (int v = 0; v < 16; ++v) {
                    uint4 x = p[v];
                    u64 nib = (u64)((x.x != 0u) | ((x.y != 0u) << 1) |
                                    ((x.z != 0u) << 2) | ((x.w != 0u) << 3));
                    bits |= nib << (v * 4);
                }
            }
            if (lim < 64) bits &= (1ull << lim) - 1ull;
        }
    }
    adjW[t] = bits;
}

// ---------------------------------------------------------------------------
// BFS body templated on WL = ceil(nn/64) in {3,4,5}: row reads, unions, and
// popcounts all touch only WL words -> ~20% fewer LDS instr, ~30% less VALU.
// Arrays stay size 5 (elements >= WL zeroed) so the segment spill read
// cur[w0+1] (w0+1 <= 4, possibly == WL) safely yields 0.
// ---------------------------------------------------------------------------
template<int WL>
__device__ __forceinline__ void bfs_core(const u64* __restrict__ adj_s,
                                         u8* __restrict__ idxrow,
                                         int nn, int sg, int k) {
    u64 valid[5] = {0,0,0,0,0};
    #pragma unroll
    for (int w = 0; w < WL; ++w) {
        int c = nn - w * 64;
        valid[w] = (c >= 64) ? ~0ull : ((c <= 0) ? 0ull : ((1ull << c) - 1ull));
    }
    u64 cur[5] = {0,0,0,0,0}, vis[5] = {0,0,0,0,0};
    if (sg < nn) {
        cur[sg >> 6] = 1ull << (sg & 63);
        vis[sg >> 6] = cur[sg >> 6];
        if (k == 0) idxrow[sg] = 1;     // dist 0 -> emb idx 1
    }
    int base = 20 * k, w0 = base >> 6, sh = base & 63;
    u8* myseg = idxrow + base;

    int level = 1;
    while (level <= Nn) {
        u64 unv[5] = {0,0,0,0,0};
        int fc = 0, uw = 0;
        #pragma unroll
        for (int w = 0; w < WL; ++w) {
            unv[w] = valid[w] & ~vis[w];
            fc += __popcll(cur[w]);
            uw += __popcll(unv[w]);
        }
        if (!__any(fc != 0)) break;

        u64 nxt[5] = {0,0,0,0,0};
        if (fc > 0 && uw > 0) {
            if (fc <= uw) {
                // top-down: 4-wide over my segment's frontier bits
                u64 f = cur[w0] >> sh;
                if (sh > 44) f |= cur[w0 + 1] << (64 - sh);
                u32 m = (u32)f & MASK20;
                while (m) {
                    int j0 = base + __builtin_ctz(m); m &= m - 1;
                    int j1 = j0, j2 = j0, j3 = j0;
                    if (m) { j1 = base + __builtin_ctz(m); m &= m - 1; }
                    if (m) { j2 = base + __builtin_ctz(m); m &= m - 1; }
                    if (m) { j3 = base + __builtin_ctz(m); m &= m - 1; }
                    const u64* r0 = adj_s + j0 * ROWW;
                    const u64* r1 = adj_s + j1 * ROWW;
                    const u64* r2 = adj_s + j2 * ROWW;
                    const u64* r3 = adj_s + j3 * ROWW;
                    ulonglong2 a0 = *(const ulonglong2*)r0;
                    ulonglong2 b0 = *(const ulonglong2*)r1;
                    ulonglong2 c0 = *(const ulonglong2*)r2;
                    ulonglong2 d0 = *(const ulonglong2*)r3;
                    nxt[0] |= (a0.x | b0.x) | (c0.x | d0.x);
                    nxt[1] |= (a0.y | b0.y) | (c0.y | d0.y);
                    if constexpr (WL >= 4) {
                        ulonglong2 a1 = *(const ulonglong2*)(r0 + 2);
                        ulonglong2 b1 = *(const ulonglong2*)(r1 + 2);
                        ulonglong2 c1 = *(const ulonglong2*)(r2 + 2);
                        ulonglong2 d1 = *(const ulonglong2*)(r3 + 2);
                        nxt[2] |= (a1.x | b1.x) | (c1.x | d1.x);
                        nxt[3] |= (a1.y | b1.y) | (c1.y | d1.y);
                        if constexpr (WL == 5) {
                            u64 a4 = r0[4], b4 = r1[4], c4 = r2[4], d4 = r3[4];
                            nxt[4] |= (a4 | b4) | (c4 | d4);
                        }
                    } else {
                        u64 a2 = r0[2], b2 = r1[2], c2 = r2[2], d2 = r3[2];
                        nxt[2] |= (a2 | b2) | (c2 | d2);
                    }
                }
            } else {
                // bottom-up: 4-wide over my unvisited segment
                u64 u_ = unv[w0] >> sh;
                if (sh > 44) u_ |= unv[w0 + 1] << (64 - sh);
                u32 m = (u32)u_ & MASK20;
                while (m) {
                    int p0 = __builtin_ctz(m); m &= m - 1;
                    int p1 = p0, p2 = p0, p3 = p0;
                    bool h1 = false, h2 = false, h3 = false;
                    if (m) { p1 = __builtin_ctz(m); m &= m - 1; h1 = true; }
                    if (m) { p2 = __builtin_ctz(m); m &= m - 1; h2 = true; }
                    if (m) { p3 = __builtin_ctz(m); m &= m - 1; h3 = true; }
                    int j0 = base + p0, j1 = base + p1;
                    int j2 = base + p2, j3 = base + p3;
                    const u64* r0 = adj_s + j0 * ROWW;
                    const u64* r1 = adj_s + j1 * ROWW;
                    const u64* r2 = adj_s + j2 * ROWW;
                    const u64* r3 = adj_s + j3 * ROWW;
                    u64 t0, t1, t2, t3;
                    {
                        ulonglong2 a0 = *(const ulonglong2*)r0;
                        ulonglong2 b0 = *(const ulonglong2*)r1;
                        ulonglong2 c0 = *(const ulonglong2*)r2;
                        ulonglong2 d0 = *(const ulonglong2*)r3;
                        t0 = (a0.x & cur[0]) | (a0.y & cur[1]);
                        t1 = (b0.x & cur[0]) | (b0.y & cur[1]);
                        t2 = (c0.x & cur[0]) | (c0.y & cur[1]);
                        t3 = (d0.x & cur[0]) | (d0.y & cur[1]);
                    }
                    if constexpr (WL >= 4) {
                        ulonglong2 a1 = *(const ulonglong2*)(r0 + 2);
                        ulonglong2 b1 = *(const ulonglong2*)(r1 + 2);
                        ulonglong2 c1 = *(const ulonglong2*)(r2 + 2);
                        ulonglong2 d1 = *(const ulonglong2*)(r3 + 2);
                        t0 |= (a1.x & cur[2]) | (a1.y & cur[3]);
                        t1 |= (b1.x & cur[2]) | (b1.y & cur[3]);
                        t2 |= (c1.x & cur[2]) | (c1.y & cur[3]);
                        t3 |= (d1.x & cur[2]) | (d1.y & cur[3]);
                        if constexpr (WL == 5) {
                            t0 |= r0[4] & cur[4];
                            t1 |= r1[4] & cur[4];
                            t2 |= r2[4] & cur[4];
                            t3 |= r3[4] & cur[4];
                        }
                    } else {
                        t0 |= r0[2] & cur[2];
                        t1 |= r1[2] & cur[2];
                        t2 |= r2[2] & cur[2];
                        t3 |= r3[2] & cur[2];
                    }
                    if (t0) nxt[j0 >> 6] |= 1ull << (j0 & 63);
                    if (h1 && t1) nxt[j1 >> 6] |= 1ull << (j1 & 63);
                    if (h2 && t2) nxt[j2 >> 6] |= 1ull << (j2 & 63);
                    if (h3 && t3) nxt[j3 >> 6] |= 1ull << (j3 & 63);
                }
            }
            // union across the source's 16 lanes: DPP row-rotate ORs (VALU)
            #pragma unroll
            for (int w = 0; w < WL; ++w) {
                u64 v = nxt[w];
                v = ror_or64<ROW_ROR_1>(v);
                v = ror_or64<ROW_ROR_2>(v);
                v = ror_or64<ROW_ROR_4>(v);
                v = ror_or64<ROW_ROR_8>(v);
                nxt[w] = v & unv[w];
            }
            u64 any = 0;
            #pragma unroll
            for (int w = 0; w < WL; ++w) any |= nxt[w];
            if (any) {
                u8 val = (u8)((level < MAXD ? level : MAXD) + 1);
                u64 f = nxt[w0] >> sh;
                if (sh > 44) f |= nxt[w0 + 1] << (64 - sh);
                u32 segn = (u32)f & MASK20;
                while (segn) { int p = __builtin_ctz(segn); segn &= segn - 1; myseg[p] = val; }
                #pragma unroll
                for (int w = 0; w < WL; ++w) vis[w] |= nxt[w];
            }
        }
        // bottom break: nothing new anywhere in the wave -> done
        u64 anyw = 0;
        #pragma unroll
        for (int w = 0; w < WL; ++w) anyw |= nxt[w];
        if (!__any(anyw != 0)) break;
        #pragma unroll
        for (int w = 0; w < WL; ++w) cur[w] = nxt[w];
        ++level;
    }
}

// ---------------------------------------------------------------------------
// Kernel 2: fused BFS + write. 640 blocks x 256 threads (graph x 16-source
// chunk; wave wv owns sources wv*4..wv*4+3; 16 lanes per source = one DPP
// row). Stage trimmed to nn rows; BFS body dispatched on WL=ceil(nn/64).
// No barrier after BFS: waves desync into the write phase.
// ---------------------------------------------------------------------------
__global__ __launch_bounds__(TPB) void bfs_write(
        const u64* __restrict__ adjW,
        const int* __restrict__ nn_,
        const float* __restrict__ emb,
        float4* __restrict__ out4) {
    int blk = blockIdx.x;
    int b = blk / NCHUNK, chunk = blk % NCHUNK;
    int t = threadIdx.x;
    int wv = t >> 6;
    int lane = t & 63;
    int s = lane >> 4;            // source-in-wave 0..3 (one DPP row)
    int k = lane & 15;            // segment 0..15 (20 nodes each)
    int r = wv * 4 + s;           // idx row 0..15

    __shared__ __align__(16) u64 adj_s[Nn * ROWW];    // 15360 B row-major
    __shared__ __align__(16) u8 idx_s[CH][IDXSTR];    // 5376 B
    __shared__ float emb_s[(MAXD + 2) * ESTR];        // 576 B

    if (t < 96) emb_s[(t >> 3) * ESTR + (t & 7)] = emb[t];

    int nn = nn_[b];

    // stage: only nn rows = nn*3 uint4 (rows >= nn are never read:
    // frontier and unvisited sets are subsets of valid = [0, nn))
    {
        int count4 = nn * 3;
        const uint4* g4 = (const uint4*)(adjW + (size_t)b * (Nn * ROWW));
        uint4* d4 = (uint4*)adj_s;
        #pragma unroll
        for (int it = 0; it < 4; ++it) {
            int i = it * TPB + t;
            if (i < count4) {
#if __has_builtin(__builtin_amdgcn_global_load_lds)
                __builtin_amdgcn_global_load_lds(
                    (const __attribute__((address_space(1))) void*)(g4 + i),
                    (__attribute__((address_space(3))) void*)(d4 + i),
                    16, 0, 0);
#else
                d4[i] = g4[i];
#endif
            }
        }
    }
    // zero idx tile (1344 u32)
    #pragma unroll
    for (int it = 0; it < 6; ++it) {
        int i = it * TPB + t;
        if (i < (CH * IDXSTR) / 4) ((u32*)idx_s)[i] = 0;
    }
    __syncthreads();   // drains vmcnt (global_load_lds) + lgkmcnt

    int sg = chunk * CH + r;
    int wlim = (nn + 63) >> 6;    // 3, 4, or 5 (nn in [161, 320])
    if (wlim == 5)      bfs_core<5>(adj_s, idx_s[r], nn, sg, k);
    else if (wlim == 4) bfs_core<4>(adj_s, idx_s[r], nn, sg, k);
    else                bfs_core<3>(adj_s, idx_s[r], nn, sg, k);

    // NO barrier: each wave reads only its own idx rows below; the faster
    // wave starts its store stream immediately.

    // ---- write phase: my wave's 4 rows x 640 float4 ----
    float4* gout = out4 + (size_t)(b * Nn + chunk * CH) * (Nn * NH / 4);
    #pragma unroll
    for (int r2 = 0; r2 < 4; ++r2) {
        int rr = wv * 4 + r2;
        const u8* irow = idx_s[rr];
        float4* rowout = gout + rr * (Nn * NH / 4);
        #pragma unroll
        for (int i = 0; i < 10; ++i) {
            int f = i * 64 + lane;                // f4 index in row, 0..639
            int e = irow[f >> 1];
            const float* ep = emb_s + e * ESTR + ((f & 1) << 2);
            rowout[f] = *(const float4*)ep;
        }
    }
}

extern "C" void kernel_launch(void* const* d_in, const int* in_sizes, int n_in,
                              void* d_out, int out_size, void* d_ws, size_t ws_size,
                              hipStream_t stream) {
    const u8*    adj = (const u8*)d_in[0];
    const int*   nn  = (const int*)d_in[1];
    const float* emb = (const float*)d_in[2];

    u64* adjW = (u64*)d_ws;

    build_adj<<<(ADJP_WORDS + 255) / 256, 256, 0, stream>>>(adj, nn, adjW);
    bfs_write<<<Bn * NCHUNK, TPB, 0, stream>>>(adjW, nn, emb, (float4*)d_out);
}